// Round 13
// baseline (5190.186 us; speedup 1.0000x reference)
//
#include <hip/hip_runtime.h>
#include <stdint.h>

// ---------------------------------------------------------------------------
// ODE-RNN encoder, f32 I/O, bf16 MFMA internals.
// R13 = R12 with the DMA addressing bug fixed: __builtin_amdgcn_global_load_lds
// loads 16B PER LANE from each lane's own global address (deposited at
// lds_base + lane*16). R12 passed a wave-uniform src -> every lane fetched the
// same 16B -> garbage weights (absmax 1.29). Fix: src += lane*16B; the tiled
// weight layout makes one frag = contiguous 1KB in exactly lane*16B order, so
// LDS content is now bit-identical to R11's direct-VGPR b-frags.
// Pipeline: per-wave 2-slot LDS buffer, group = 4 frags (4KB), explicit
// s_waitcnt vmcnt(4)/(0) (compiler cannot sink DMAs), no K-loop barriers,
// lgkm-only epilogue barriers so primed DMAs fly across GEMM boundaries.
// ---------------------------------------------------------------------------

typedef __bf16 bf16x8 __attribute__((ext_vector_type(8)));
typedef float floatx4 __attribute__((ext_vector_type(4)));

#define BP 40  // gru_step padded B row (ushorts)

static __device__ __forceinline__ float bf2f(unsigned short u) {
  union { unsigned int u32; float f; } c;
  c.u32 = ((unsigned int)u) << 16;
  return c.f;
}
static __device__ __forceinline__ unsigned short f2bf(float f) {
  union { __bf16 h; unsigned short u; } c;
  c.h = (__bf16)f;  // RNE
  return c.u;
}

// LDS-only barrier: does NOT drain vmcnt, so DMA prefetches stay in flight.
static __device__ __forceinline__ void barrier_lds() {
  __asm__ volatile("s_waitcnt lgkmcnt(0)\n\ts_barrier" ::: "memory");
}

// async global->LDS, 16B per lane: lane l loads g + l*16B, lands at l + l*16B.
static __device__ __forceinline__ void gl2lds(const unsigned short* g, unsigned short* l) {
  __builtin_amdgcn_global_load_lds((__attribute__((address_space(1))) void*)(g),
                                   (__attribute__((address_space(3))) void*)(l), 16, 0, 0);
}

// ---------------------------------------------------------------------------
// tile_weight: W (K=512 x N=512, f32 row-major) -> bf16 tiled
// [kk(16)][nt(32)][qd(4)][ml(16)][8]; element (kk,nt,qd,ml,j) = W[kk*32+qd*8+j][nt*16+ml]
// One (kk,nt) frag = contiguous 1KB whose internal order is lane*16B.
// ---------------------------------------------------------------------------
__global__ void tile_weight(const float* __restrict__ src, unsigned short* __restrict__ dst) {
  int t = blockIdx.x * 256 + threadIdx.x;  // 0..32767
  int ml = t & 15, qd = (t >> 4) & 3;
  int nt = (t >> 6) & 31, kk = t >> 11;
  int n = nt * 16 + ml;
  int k0 = kk * 32 + qd * 8;
  unsigned short o[8] __attribute__((aligned(16)));
#pragma unroll
  for (int j = 0; j < 8; ++j) o[j] = f2bf(src[(size_t)(k0 + j) * 512 + n]);
  *(uint4*)(dst + (size_t)t * 8) = *(const uint4*)o;
}

// ---------------------------------------------------------------------------
// transpose + f32->bf16 (GRU weights, [n][k] flat layout)
// ---------------------------------------------------------------------------
__global__ void transpose_f2b(const float* __restrict__ src, unsigned short* __restrict__ dst,
                              int R, int C) {
  __shared__ float t[32][33];
  int c0 = blockIdx.x * 32, r0 = blockIdx.y * 32;
  int tx = threadIdx.x, ty = threadIdx.y;  // 32 x 8
#pragma unroll
  for (int i = 0; i < 32; i += 8) t[ty + i][tx] = src[(size_t)(r0 + ty + i) * C + c0 + tx];
  __syncthreads();
#pragma unroll
  for (int i = 0; i < 32; i += 8) dst[(size_t)(c0 + ty + i) * R + r0 + tx] = f2bf(t[tx][ty + i]);
}

// ---------------------------------------------------------------------------
// obs embed: y = leaky(LN(xs @ W + b)) (f32 in, bf16 out), one wave per row
// ---------------------------------------------------------------------------
__global__ __launch_bounds__(256) void obs_embed(
    const float* __restrict__ xs, const float* __restrict__ W,
    const float* __restrict__ bias, const float* __restrict__ gam,
    const float* __restrict__ bet, unsigned short* __restrict__ Y) {
  __shared__ float Wl[4096];
  const int tid = threadIdx.x, lane = tid & 63, wv = tid >> 6;
#pragma unroll
  for (int i = 0; i < 16; ++i) Wl[i * 256 + tid] = W[i * 256 + tid];
  __syncthreads();
  size_t row = (size_t)blockIdx.x * 4 + wv;
  float xf[8];
  {
    const float* xp = xs + row * 8;
#pragma unroll
    for (int k = 0; k < 8; ++k) xf[k] = xp[k];
  }
  int n0 = lane * 8;
  float a[8];
#pragma unroll
  for (int j = 0; j < 8; ++j) a[j] = bias[n0 + j];
#pragma unroll
  for (int k = 0; k < 8; ++k)
#pragma unroll
    for (int j = 0; j < 8; ++j) a[j] += xf[k] * Wl[k * 512 + n0 + j];
  float s1 = 0.f, s2 = 0.f;
#pragma unroll
  for (int j = 0; j < 8; ++j) { s1 += a[j]; s2 += a[j] * a[j]; }
#pragma unroll
  for (int off = 1; off < 64; off <<= 1) { s1 += __shfl_xor(s1, off); s2 += __shfl_xor(s2, off); }
  float mean = s1 * (1.f / 512.f);
  float rstd = rsqrtf(s2 * (1.f / 512.f) - mean * mean + 1e-5f);
  unsigned short o[8] __attribute__((aligned(16)));
#pragma unroll
  for (int j = 0; j < 8; ++j) {
    float v = (a[j] - mean) * rstd * gam[n0 + j] + bet[n0 + j];
    v = v > 0.f ? v : 0.01f * v;
    o[j] = f2bf(v);
  }
  *(uint4*)(Y + row * 512 + n0) = *(const uint4*)o;
}

// ---------------------------------------------------------------------------
// ODE megakernel. A (32x512) resident in tiled LDS; 4 waves, each owning
// M=32 x N=128. B: per-wave async DMA pipeline, group = 4 frags (4KB),
// 2 slots/wave, explicit vmcnt waits. No K-loop barriers.
// ---------------------------------------------------------------------------

// element (row, n) address in tiled A (ushort index), row < 32
static __device__ __forceinline__ int a_addr(int row, int n) {
  return (((row >> 4) * 16 + (n >> 5)) * 4 + ((n >> 3) & 3)) * 128 + (row & 15) * 8 + (n & 7);
}

// issue DMA for group g (4 frags): cols kk*32 + 8*wv + half*4 + j.
// NOTE: global address is PER-LANE (src + lane*16B); LDS lands at dst + lane*16B.
static __device__ __forceinline__ void dma_group(const unsigned short* __restrict__ Wt, int g,
                                                 int wv, int lane, unsigned short* BsW) {
  const unsigned short* src =
      Wt + ((size_t)(g >> 1) * 32 + 8 * wv + (g & 1) * 4) * 512 + (size_t)lane * 8;
  unsigned short* dst = BsW + (g & 1) * 2048;
#pragma unroll
  for (int j = 0; j < 4; ++j) gl2lds(src + j * 512, dst + j * 512);
}

// Pipeline invariant: on entry, groups {0,1} of Wt are in flight (primed by
// previous gemm's tail or kernel prologue). On exit, groups {0,1} of Wnext
// are in flight.
static __device__ __forceinline__ void gemm32(const unsigned short* __restrict__ Wt,
                                              const unsigned short* __restrict__ Wnext,
                                              const unsigned short* As, unsigned short* BsW,
                                              int wv, int lane, floatx4 (&acc)[2][8]) {
#pragma unroll
  for (int mi = 0; mi < 2; ++mi)
#pragma unroll
    for (int j = 0; j < 8; ++j) acc[mi][j] = 0.f;
  bf16x8 a[2];
#pragma unroll 2
  for (int g = 0; g < 30; ++g) {
    int kk = g >> 1, half = g & 1;
    if (half == 0) {
#pragma unroll
      for (int mi = 0; mi < 2; ++mi)
        a[mi] = *(const bf16x8*)&As[(mi * 16 + kk) * 512 + lane * 8];
    }
    // wait until group g's 4 DMAs landed (g+1's 4 remain outstanding)
    __asm__ volatile("s_waitcnt vmcnt(4)" ::: "memory");
    bf16x8 b[4];
#pragma unroll
    for (int j = 0; j < 4; ++j) b[j] = *(const bf16x8*)&BsW[half * 2048 + j * 512 + lane * 8];
#pragma unroll
    for (int mi = 0; mi < 2; ++mi)
#pragma unroll
      for (int j = 0; j < 4; ++j)
        acc[mi][half * 4 + j] = __builtin_amdgcn_mfma_f32_16x16x32_bf16(
            a[mi], b[j], acc[mi][half * 4 + j], 0, 0, 0);
    dma_group(Wt, g + 2, wv, lane, BsW);  // refill just-consumed slot
  }
  {  // g = 30 (slot 0): group 31 still outstanding
#pragma unroll
    for (int mi = 0; mi < 2; ++mi) a[mi] = *(const bf16x8*)&As[(mi * 16 + 15) * 512 + lane * 8];
    __asm__ volatile("s_waitcnt vmcnt(4)" ::: "memory");
    bf16x8 b[4];
#pragma unroll
    for (int j = 0; j < 4; ++j) b[j] = *(const bf16x8*)&BsW[j * 512 + lane * 8];
#pragma unroll
    for (int mi = 0; mi < 2; ++mi)
#pragma unroll
      for (int j = 0; j < 4; ++j)
        acc[mi][j] = __builtin_amdgcn_mfma_f32_16x16x32_bf16(a[mi], b[j], acc[mi][j], 0, 0, 0);
  }
  {  // g = 31 (slot 1): last group -> full drain
    __asm__ volatile("s_waitcnt vmcnt(0)" ::: "memory");
    bf16x8 b[4];
#pragma unroll
    for (int j = 0; j < 4; ++j) b[j] = *(const bf16x8*)&BsW[2048 + j * 512 + lane * 8];
#pragma unroll
    for (int mi = 0; mi < 2; ++mi)
#pragma unroll
      for (int j = 0; j < 4; ++j)
        acc[mi][4 + j] = __builtin_amdgcn_mfma_f32_16x16x32_bf16(a[mi], b[j], acc[mi][4 + j], 0, 0, 0);
  }
  // prime next gemm's groups 0,1: lands during the upcoming epilogue
  dma_group(Wnext, 0, wv, lane, BsW);
  dma_group(Wnext, 1, wv, lane, BsW);
}

// LN + leaky epilogue; writes bf16 result into tiled As.
static __device__ __forceinline__ void ln_epi32(floatx4 (&acc)[2][8], unsigned short* As,
                                                const unsigned short* Ps, int pb, int pg, int pbe,
                                                bool addt, float tval, int wv, int lane, int tid,
                                                float2* red, float* stat) {
  const int ml = lane & 15, qd = lane >> 4;
#pragma unroll
  for (int j = 0; j < 8; ++j) {
    int n = (8 * wv + j) * 16 + ml;
    float bias = bf2f(Ps[pb * 512 + n]);
    if (addt) bias += tval * bf2f(Ps[512 + n]);
#pragma unroll
    for (int mi = 0; mi < 2; ++mi)
#pragma unroll
      for (int r = 0; r < 4; ++r) acc[mi][j][r] += bias;
  }
#pragma unroll
  for (int mi = 0; mi < 2; ++mi)
#pragma unroll
    for (int r = 0; r < 4; ++r) {
      float s1 = 0.f, s2 = 0.f;
#pragma unroll
      for (int j = 0; j < 8; ++j) { float x = acc[mi][j][r]; s1 += x; s2 += x * x; }
#pragma unroll
      for (int off = 1; off < 16; off <<= 1) { s1 += __shfl_xor(s1, off); s2 += __shfl_xor(s2, off); }
      if (ml == 0) red[(mi * 16 + 4 * qd + r) * 4 + wv] = make_float2(s1, s2);
    }
  barrier_lds();  // red visible; all waves past their As a-frag reads
  if (tid < 32) {
    float S1 = 0.f, S2 = 0.f;
#pragma unroll
    for (int w = 0; w < 4; ++w) { float2 v = red[tid * 4 + w]; S1 += v.x; S2 += v.y; }
    float mean = S1 * (1.f / 512.f);
    float var = S2 * (1.f / 512.f) - mean * mean;
    stat[tid * 2] = mean;
    stat[tid * 2 + 1] = rsqrtf(var + 1e-5f);
  }
  barrier_lds();
#pragma unroll
  for (int mi = 0; mi < 2; ++mi)
#pragma unroll
    for (int r = 0; r < 4; ++r) {
      int row = mi * 16 + 4 * qd + r;
      float mean = stat[row * 2], rstd = stat[row * 2 + 1];
#pragma unroll
      for (int j = 0; j < 8; ++j) {
        int n = (8 * wv + j) * 16 + ml;
        float x = (acc[mi][j][r] - mean) * rstd * bf2f(Ps[pg * 512 + n]) + bf2f(Ps[pbe * 512 + n]);
        x = x > 0.f ? x : 0.01f * x;
        As[a_addr(row, n)] = f2bf(x);
      }
    }
  barrier_lds();  // As writes visible
}

// RK4 stage: k = acc + bout; h fp32 regs, ksum packed bf16 pairs; writes y
// into As; on the final stage also writes h_ode to Yb.
static __device__ __forceinline__ void stage_epi32(floatx4 (&acc)[2][8], float (&h)[2][8][4],
                                                   unsigned int (&ks)[2][8][2], unsigned short* As,
                                                   unsigned short* Yb, size_t m0,
                                                   const unsigned short* Ps, int stg, bool last,
                                                   int wv, int lane) {
  const int ml = lane & 15, qd = lane >> 4;
  barrier_lds();  // K-loop has no barriers: ensure all waves done reading As
#pragma unroll
  for (int mi = 0; mi < 2; ++mi)
#pragma unroll
    for (int j = 0; j < 8; ++j) {
      int n = (8 * wv + j) * 16 + ml;
      float bias = bf2f(Ps[7 * 512 + n]);
#pragma unroll
      for (int rp = 0; rp < 2; ++rp) {
        float kv0 = acc[mi][j][2 * rp] + bias;
        float kv1 = acc[mi][j][2 * rp + 1] + bias;
        unsigned int pk = ks[mi][j][rp];
        float s0 = bf2f((unsigned short)(pk & 0xffffu));
        float s1 = bf2f((unsigned short)(pk >> 16));
        float h0 = h[mi][j][2 * rp], h1 = h[mi][j][2 * rp + 1];
        float y0, y1;
        if (stg == 0)      { s0 = kv0;        s1 = kv1;        y0 = h0 + 0.125f * kv0; y1 = h1 + 0.125f * kv1; }
        else if (stg == 1) { s0 += 2.f * kv0; s1 += 2.f * kv1; y0 = h0 + 0.125f * kv0; y1 = h1 + 0.125f * kv1; }
        else if (stg == 2) { s0 += 2.f * kv0; s1 += 2.f * kv1; y0 = h0 + 0.25f * kv0;  y1 = h1 + 0.25f * kv1; }
        else {
          h0 += (1.f / 24.f) * (s0 + kv0);  // dt/6, dt=0.25
          h1 += (1.f / 24.f) * (s1 + kv1);
          h[mi][j][2 * rp] = h0; h[mi][j][2 * rp + 1] = h1;
          y0 = h0; y1 = h1;
        }
        ks[mi][j][rp] = (unsigned int)f2bf(s0) | ((unsigned int)f2bf(s1) << 16);
        int row = mi * 16 + 4 * qd + 2 * rp;
        As[a_addr(row, n)] = f2bf(y0);
        As[a_addr(row + 1, n)] = f2bf(y1);
        if (last && stg == 3) {
          Yb[(m0 + row) * 512 + n] = f2bf(y0);
          Yb[(m0 + row + 1) * 512 + n] = f2bf(y1);
        }
      }
    }
  barrier_lds();  // As writes visible
}

__global__ __launch_bounds__(256) void ode_mega(
    unsigned short* Yb, const unsigned short* __restrict__ W1t,
    const unsigned short* __restrict__ W2t, const unsigned short* __restrict__ Wot,
    const float* __restrict__ b1, const float* __restrict__ tr, const float* __restrict__ g1,
    const float* __restrict__ be1, const float* __restrict__ b2, const float* __restrict__ g2,
    const float* __restrict__ be2, const float* __restrict__ bo) {
  __shared__ __align__(16) unsigned short As[16384];  // 32KB tiled A (32 rows)
  __shared__ __align__(16) unsigned short Bs[16384];  // 32KB: 4 waves x 2 slots x 4KB
  __shared__ __align__(16) unsigned short Ps[4096];   // 8KB params
  __shared__ float2 red[128];                         // 1KB
  __shared__ float stat[64];                          // 256B -> 75008B, 2 blocks/CU

  const int tid = threadIdx.x;
  const int lane = tid & 63;
  const int wv = tid >> 6;  // 0..3
  const int ml = lane & 15;
  const int qd = lane >> 4;
  const size_t m0 = (size_t)blockIdx.x * 32;
  unsigned short* BsW = Bs + wv * 4096;  // this wave's 2-slot region

  {
    const float* srcs[8] = {b1, tr, g1, be1, b2, g2, be2, bo};
#pragma unroll
    for (int v = 0; v < 8; ++v) {
      Ps[v * 512 + tid] = f2bf(srcs[v][tid]);
      Ps[v * 512 + 256 + tid] = f2bf(srcs[v][256 + tid]);
    }
  }
  // stage As: thread owns row r = tid>>3, chunks c = i*8 + (tid&7)
  {
    int r = tid >> 3;  // 0..31
#pragma unroll
    for (int i = 0; i < 8; ++i) {
      int c = i * 8 + (tid & 7);
      uint4 v = *(const uint4*)(Yb + (m0 + r) * 512 + c * 8);
      int dst = (((r >> 4) * 16 + (c >> 2)) * 4 + (c & 3)) * 128 + (r & 15) * 8;
      *(uint4*)(As + dst) = v;
    }
  }
  // prime the DMA pipeline; these 8 DMAs fly across the lgkm-only barrier
  dma_group(W1t, 0, wv, lane, BsW);
  dma_group(W1t, 1, wv, lane, BsW);
  barrier_lds();

  float h[2][8][4];          // fp32 ODE state, MFMA C-layout
  unsigned int ks[2][8][2];  // RK4 ksum, packed bf16 pairs
#pragma unroll
  for (int mi = 0; mi < 2; ++mi)
#pragma unroll
    for (int j = 0; j < 8; ++j) {
      ks[mi][j][0] = 0u; ks[mi][j][1] = 0u;
      int n = (8 * wv + j) * 16 + ml;
#pragma unroll
      for (int r = 0; r < 4; ++r) h[mi][j][r] = bf2f(As[a_addr(mi * 16 + 4 * qd + r, n)]);
    }

  for (int e = 0; e < 16; ++e) {  // 4 RK4 steps x 4 stages
    int stg = e & 3;
    float tval = 0.25f * (float)(e >> 2) + ((stg == 3) ? 0.25f : (stg ? 0.125f : 0.f));
    floatx4 acc[2][8];
    gemm32(W1t, W2t, As, BsW, wv, lane, acc);
    ln_epi32(acc, As, Ps, 0, 2, 3, true, tval, wv, lane, tid, red, stat);
    gemm32(W2t, Wot, As, BsW, wv, lane, acc);
    ln_epi32(acc, As, Ps, 4, 5, 6, false, 0.f, wv, lane, tid, red, stat);
    gemm32(Wot, W1t, As, BsW, wv, lane, acc);  // primes next eval's W1
    stage_epi32(acc, h, ks, As, Yb, m0, Ps, stg, e == 15, wv, lane);
  }
}

// ---------------------------------------------------------------------------
// GRU step (unchanged): gi = y_t @ W_ih, gh = h_prev @ W_hh, gates.
// grid (32, 8): 32 rows x 64 gate-cols per block, 4 waves.
// ---------------------------------------------------------------------------
__global__ __launch_bounds__(256) void gru_step(
    const unsigned short* __restrict__ Yt, const float* __restrict__ hprev,
    float* __restrict__ hnew, const unsigned short* __restrict__ Wiht,
    const unsigned short* __restrict__ Whht, const float* __restrict__ bih,
    const float* __restrict__ bhh) {
  __shared__ __align__(16) unsigned short Ay[32 * BP];
  __shared__ __align__(16) unsigned short Ah[32 * BP];
  __shared__ __align__(16) unsigned short Bg[6 * 64 * BP];
  const int tid = threadIdx.x, lane = tid & 63, wv = tid >> 6;
  const int ml = lane & 15, qd = lane >> 4;
  const int m0 = blockIdx.x * 32;
  const int j0 = blockIdx.y * 64;

  floatx4 acc[2][6];
#pragma unroll
  for (int mi = 0; mi < 2; ++mi)
#pragma unroll
    for (int g = 0; g < 6; ++g) acc[mi][g] = 0.f;

  for (int kk = 0; kk < 16; ++kk) {
    __syncthreads();
#pragma unroll
    for (int c = 0; c < 7; ++c) {
      int id = c * 256 + tid;
      if (id < 128) {
        int r = id >> 2, kc = id & 3;
        *(uint4*)(Ay + r * BP + kc * 8) =
            *(const uint4*)(Yt + (size_t)(m0 + r) * 512 + kk * 32 + kc * 8);
      } else if (id < 256) {
        int id2 = id - 128;
        int r = id2 >> 2, kc = id2 & 3;
        const float* s = hprev + (size_t)(m0 + r) * 512 + kk * 32 + kc * 8;
        unsigned short o[8] __attribute__((aligned(16)));
#pragma unroll
        for (int j = 0; j < 8; ++j) o[j] = f2bf(s[j]);
        *(uint4*)(Ah + r * BP + kc * 8) = *(const uint4*)o;
      } else {
        int id2 = id - 256;
        int g = id2 >> 8;
        int rem = id2 & 255;
        int r = rem >> 2, kc = rem & 3;
        const unsigned short* mat = (g < 3) ? Wiht : Whht;
        int gate = (g < 3) ? g : (g - 3);
        *(uint4*)(Bg + g * (64 * BP) + r * BP + kc * 8) =
            *(const uint4*)(mat + (size_t)(gate * 512 + j0 + r) * 512 + kk * 32 + kc * 8);
      }
    }
    __syncthreads();
    bf16x8 ay[2], ah[2];
#pragma unroll
    for (int mi = 0; mi < 2; ++mi) {
      ay[mi] = *(const bf16x8*)&Ay[(16 * mi + ml) * BP + qd * 8];
      ah[mi] = *(const bf16x8*)&Ah[(16 * mi + ml) * BP + qd * 8];
    }
#pragma unroll
    for (int g = 0; g < 6; ++g) {
      bf16x8 b = *(const bf16x8*)&Bg[g * (64 * BP) + (16 * wv + ml) * BP + qd * 8];
#pragma unroll
      for (int mi = 0; mi < 2; ++mi)
        acc[mi][g] = __builtin_amdgcn_mfma_f32_16x16x32_bf16((g < 3) ? ay[mi] : ah[mi], b,
                                                             acc[mi][g], 0, 0, 0);
    }
  }
  int j = j0 + 16 * wv + ml;
  float bi_r = bih[j], bi_z = bih[512 + j], bi_n = bih[1024 + j];
  float bh_r = bhh[j], bh_z = bhh[512 + j], bh_n = bhh[1024 + j];
#pragma unroll
  for (int mi = 0; mi < 2; ++mi)
#pragma unroll
    for (int r = 0; r < 4; ++r) {
      size_t row = (size_t)(m0 + 16 * mi + 4 * qd + r);
      float rg = acc[mi][0][r] + bi_r + acc[mi][3][r] + bh_r;
      rg = 1.f / (1.f + __expf(-rg));
      float zg = acc[mi][1][r] + bi_z + acc[mi][4][r] + bh_z;
      zg = 1.f / (1.f + __expf(-zg));
      float ng = tanhf(acc[mi][2][r] + bi_n + rg * (acc[mi][5][r] + bh_n));
      float hp = hprev[row * 512 + j];
      hnew[row * 512 + j] = (1.f - zg) * ng + zg * hp;
    }
}

__global__ void zero_h(float* hf) {
  int i = blockIdx.x * 256 + threadIdx.x;
  hf[i] = 0.f;
}

// ---------------------------------------------------------------------------
extern "C" void kernel_launch(void* const* d_in, const int* in_sizes, int n_in,
                              void* d_out, int out_size, void* d_ws, size_t ws_size,
                              hipStream_t stream) {
  (void)in_sizes; (void)n_in; (void)out_size; (void)ws_size;
  const float* xs    = (const float*)d_in[0];
  const float* obsW  = (const float*)d_in[1];
  const float* obsb  = (const float*)d_in[2];
  const float* obsg  = (const float*)d_in[3];
  const float* obsbe = (const float*)d_in[4];
  const float* W1    = (const float*)d_in[5];
  const float* b1    = (const float*)d_in[6];
  const float* g1    = (const float*)d_in[7];
  const float* be1   = (const float*)d_in[8];
  const float* W2    = (const float*)d_in[9];
  const float* b2    = (const float*)d_in[10];
  const float* g2    = (const float*)d_in[11];
  const float* be2   = (const float*)d_in[12];
  const float* Wo    = (const float*)d_in[13];
  const float* bo    = (const float*)d_in[14];
  const float* Wih   = (const float*)d_in[15];
  const float* bih   = (const float*)d_in[16];
  const float* Whh   = (const float*)d_in[17];
  const float* bhh   = (const float*)d_in[18];

  char* p = (char*)d_ws;
  auto take = [&](size_t bytes) { char* q = p; p += (bytes + 255) & ~(size_t)255; return q; };
  unsigned short* W1t  = (unsigned short*)take((size_t)512 * 512 * 2);
  unsigned short* W2t  = (unsigned short*)take((size_t)512 * 512 * 2);
  unsigned short* Wot  = (unsigned short*)take((size_t)512 * 512 * 2);
  unsigned short* Wiht = (unsigned short*)take((size_t)1536 * 512 * 2);
  unsigned short* Whht = (unsigned short*)take((size_t)1536 * 512 * 2);
  float* hf0 = (float*)take((size_t)1024 * 512 * 4);
  float* hf1 = (float*)take((size_t)1024 * 512 * 4);
  unsigned short* Yb = (unsigned short*)take((size_t)65536 * 512 * 2);

  dim3 tb(32, 8);
  tile_weight<<<128, 256, 0, stream>>>(W1, W1t);  // first 512 of 513 rows
  tile_weight<<<128, 256, 0, stream>>>(W2, W2t);
  tile_weight<<<128, 256, 0, stream>>>(Wo, Wot);
  transpose_f2b<<<dim3(48, 16), tb, 0, stream>>>(Wih, Wiht, 512, 1536);
  transpose_f2b<<<dim3(48, 16), tb, 0, stream>>>(Whh, Whht, 512, 1536);

  obs_embed<<<16384, 256, 0, stream>>>(xs, obsW, obsb, obsg, obsbe, Yb);

  // tr = W1 row 512 (time row), folded into layer-1 bias per eval.
  ode_mega<<<2048, 256, 0, stream>>>(Yb, W1t, W2t, Wot, b1, W1 + 512 * 512, g1, be1, b2, g2,
                                     be2, bo);

  zero_h<<<2048, 256, 0, stream>>>(hf0);
  float* hf[2] = {hf0, hf1};
  for (int t = 0; t < 64; ++t) {
    int s = t & 1, d = s ^ 1;
    float* hn = (t == 63) ? (float*)d_out : hf[d];
    gru_step<<<dim3(32, 8), 256, 0, stream>>>(Yb + (size_t)t * 1024 * 512, hf[s], hn, Wiht, Whht,
                                              bih, bhh);
  }
}

// Round 14
// 4085.475 us; speedup vs baseline: 1.2704x; 1.2704x over previous
//
#include <hip/hip_runtime.h>
#include <stdint.h>

// ---------------------------------------------------------------------------
// ODE-RNN encoder, f32 I/O, bf16 MFMA internals.
// R14: TLP doubling. 512-thr ode_mega blocks, M=32 rows, 8 waves each owning
// M=32 x N=64 -> per-wave state acc32+h32+ks16+bb32+a8 ~= 120 fits the
// measured 128-reg budget (131072/(2*512)). 2 blocks/CU -> 16 waves/CU
// (4/SIMD), double R10-R13's latency-hiding streams. B: direct global->VGPR
// 2-slab dbuf (R10/R11-proven; R12/R13's DMA+LDS round-trip regressed).
// K-loop barrier-free, epilogue barriers lgkm-only, K-loop unroll 2.
// ---------------------------------------------------------------------------

typedef __bf16 bf16x8 __attribute__((ext_vector_type(8)));
typedef float floatx4 __attribute__((ext_vector_type(4)));

#define BP 40  // gru_step padded B row (ushorts)

static __device__ __forceinline__ float bf2f(unsigned short u) {
  union { unsigned int u32; float f; } c;
  c.u32 = ((unsigned int)u) << 16;
  return c.f;
}
static __device__ __forceinline__ unsigned short f2bf(float f) {
  union { __bf16 h; unsigned short u; } c;
  c.h = (__bf16)f;  // RNE
  return c.u;
}

// LDS-only barrier: does NOT drain vmcnt, so global prefetches stay in flight.
static __device__ __forceinline__ void barrier_lds() {
  __asm__ volatile("s_waitcnt lgkmcnt(0)\n\ts_barrier" ::: "memory");
}

// ---------------------------------------------------------------------------
// tile_weight: W (K=512 x N=512, f32 row-major) -> bf16 tiled
// [kk(16)][nt(32)][qd(4)][ml(16)][8]; element (kk,nt,qd,ml,j) = W[kk*32+qd*8+j][nt*16+ml]
// ---------------------------------------------------------------------------
__global__ void tile_weight(const float* __restrict__ src, unsigned short* __restrict__ dst) {
  int t = blockIdx.x * 256 + threadIdx.x;  // 0..32767
  int ml = t & 15, qd = (t >> 4) & 3;
  int nt = (t >> 6) & 31, kk = t >> 11;
  int n = nt * 16 + ml;
  int k0 = kk * 32 + qd * 8;
  unsigned short o[8] __attribute__((aligned(16)));
#pragma unroll
  for (int j = 0; j < 8; ++j) o[j] = f2bf(src[(size_t)(k0 + j) * 512 + n]);
  *(uint4*)(dst + (size_t)t * 8) = *(const uint4*)o;
}

// ---------------------------------------------------------------------------
// transpose + f32->bf16 (GRU weights, [n][k] flat layout)
// ---------------------------------------------------------------------------
__global__ void transpose_f2b(const float* __restrict__ src, unsigned short* __restrict__ dst,
                              int R, int C) {
  __shared__ float t[32][33];
  int c0 = blockIdx.x * 32, r0 = blockIdx.y * 32;
  int tx = threadIdx.x, ty = threadIdx.y;  // 32 x 8
#pragma unroll
  for (int i = 0; i < 32; i += 8) t[ty + i][tx] = src[(size_t)(r0 + ty + i) * C + c0 + tx];
  __syncthreads();
#pragma unroll
  for (int i = 0; i < 32; i += 8) dst[(size_t)(c0 + ty + i) * R + r0 + tx] = f2bf(t[tx][ty + i]);
}

// ---------------------------------------------------------------------------
// obs embed: y = leaky(LN(xs @ W + b)) (f32 in, bf16 out), one wave per row
// ---------------------------------------------------------------------------
__global__ __launch_bounds__(256) void obs_embed(
    const float* __restrict__ xs, const float* __restrict__ W,
    const float* __restrict__ bias, const float* __restrict__ gam,
    const float* __restrict__ bet, unsigned short* __restrict__ Y) {
  __shared__ float Wl[4096];
  const int tid = threadIdx.x, lane = tid & 63, wv = tid >> 6;
#pragma unroll
  for (int i = 0; i < 16; ++i) Wl[i * 256 + tid] = W[i * 256 + tid];
  __syncthreads();
  size_t row = (size_t)blockIdx.x * 4 + wv;
  float xf[8];
  {
    const float* xp = xs + row * 8;
#pragma unroll
    for (int k = 0; k < 8; ++k) xf[k] = xp[k];
  }
  int n0 = lane * 8;
  float a[8];
#pragma unroll
  for (int j = 0; j < 8; ++j) a[j] = bias[n0 + j];
#pragma unroll
  for (int k = 0; k < 8; ++k)
#pragma unroll
    for (int j = 0; j < 8; ++j) a[j] += xf[k] * Wl[k * 512 + n0 + j];
  float s1 = 0.f, s2 = 0.f;
#pragma unroll
  for (int j = 0; j < 8; ++j) { s1 += a[j]; s2 += a[j] * a[j]; }
#pragma unroll
  for (int off = 1; off < 64; off <<= 1) { s1 += __shfl_xor(s1, off); s2 += __shfl_xor(s2, off); }
  float mean = s1 * (1.f / 512.f);
  float rstd = rsqrtf(s2 * (1.f / 512.f) - mean * mean + 1e-5f);
  unsigned short o[8] __attribute__((aligned(16)));
#pragma unroll
  for (int j = 0; j < 8; ++j) {
    float v = (a[j] - mean) * rstd * gam[n0 + j] + bet[n0 + j];
    v = v > 0.f ? v : 0.01f * v;
    o[j] = f2bf(v);
  }
  *(uint4*)(Y + row * 512 + n0) = *(const uint4*)o;
}

// ---------------------------------------------------------------------------
// ODE megakernel. A (32x512) resident in tiled LDS [mt][kk][qd][ml][8];
// 8 waves, each owning M=32 (2 mt) x N=64 (nt = 4*wv .. 4*wv+3).
// B fragments stream global->VGPR dbuf; K-loop barrier-free.
// ---------------------------------------------------------------------------

// element (row, n) address in tiled A (ushort index), row < 32
static __device__ __forceinline__ int a_addr(int row, int n) {
  return (((row >> 4) * 16 + (n >> 5)) * 4 + ((n >> 3) & 3)) * 128 + (row & 15) * 8 + (n & 7);
}

static __device__ __forceinline__ void bload(const unsigned short* __restrict__ Wt, int kk,
                                             int wv, int lane, bf16x8 (&b)[4]) {
#pragma unroll
  for (int j = 0; j < 4; ++j)
    b[j] = *(const bf16x8*)(Wt + ((size_t)kk * 32 + 4 * wv + j) * 512 + (size_t)lane * 8);
}

// bb must hold Wt slabs {0,1} on entry; holds Wnext slabs {0,1} on exit.
static __device__ __forceinline__ void gemmS(const unsigned short* __restrict__ Wt,
                                             const unsigned short* __restrict__ Wnext,
                                             const unsigned short* As, int wv, int lane,
                                             bf16x8 (&bb)[2][4], floatx4 (&acc)[2][4]) {
#pragma unroll
  for (int mi = 0; mi < 2; ++mi)
#pragma unroll
    for (int j = 0; j < 4; ++j) acc[mi][j] = 0.f;
#pragma unroll 2
  for (int kk = 0; kk < 16; ++kk) {  // unroll 2 (dbuf parity), NOT full (R5-R8 lesson)
    bf16x8 a[2];
#pragma unroll
    for (int mi = 0; mi < 2; ++mi) a[mi] = *(const bf16x8*)&As[(mi * 16 + kk) * 512 + lane * 8];
#pragma unroll
    for (int mi = 0; mi < 2; ++mi)
#pragma unroll
      for (int j = 0; j < 4; ++j)
        acc[mi][j] =
            __builtin_amdgcn_mfma_f32_16x16x32_bf16(a[mi], bb[kk & 1][j], acc[mi][j], 0, 0, 0);
    // refill the just-consumed slot: kk+2 of this weight, or next weight's 0/1
    if (kk < 14) bload(Wt, kk + 2, wv, lane, bb[kk & 1]);
    else bload(Wnext, kk - 14, wv, lane, bb[kk & 1]);
  }
}

// LN + leaky epilogue; 8-wave reduction; writes bf16 result into tiled As.
static __device__ __forceinline__ void ln_epi(floatx4 (&acc)[2][4], unsigned short* As,
                                              const unsigned short* Ps, int pb, int pg, int pbe,
                                              bool addt, float tval, int wv, int lane, int tid,
                                              float2* red, float* stat) {
  const int ml = lane & 15, qd = lane >> 4;
#pragma unroll
  for (int j = 0; j < 4; ++j) {
    int n = (4 * wv + j) * 16 + ml;
    float bias = bf2f(Ps[pb * 512 + n]);
    if (addt) bias += tval * bf2f(Ps[512 + n]);
#pragma unroll
    for (int mi = 0; mi < 2; ++mi)
#pragma unroll
      for (int r = 0; r < 4; ++r) acc[mi][j][r] += bias;
  }
#pragma unroll
  for (int mi = 0; mi < 2; ++mi)
#pragma unroll
    for (int r = 0; r < 4; ++r) {
      float s1 = 0.f, s2 = 0.f;
#pragma unroll
      for (int j = 0; j < 4; ++j) { float x = acc[mi][j][r]; s1 += x; s2 += x * x; }
#pragma unroll
      for (int off = 1; off < 16; off <<= 1) { s1 += __shfl_xor(s1, off); s2 += __shfl_xor(s2, off); }
      if (ml == 0) red[(mi * 16 + 4 * qd + r) * 8 + wv] = make_float2(s1, s2);
    }
  barrier_lds();  // red visible; all waves past their As a-frag reads
  if (tid < 32) {
    float S1 = 0.f, S2 = 0.f;
#pragma unroll
    for (int w = 0; w < 8; ++w) { float2 v = red[tid * 8 + w]; S1 += v.x; S2 += v.y; }
    float mean = S1 * (1.f / 512.f);
    float var = S2 * (1.f / 512.f) - mean * mean;
    stat[tid * 2] = mean;
    stat[tid * 2 + 1] = rsqrtf(var + 1e-5f);
  }
  barrier_lds();
#pragma unroll
  for (int mi = 0; mi < 2; ++mi)
#pragma unroll
    for (int r = 0; r < 4; ++r) {
      int row = mi * 16 + 4 * qd + r;
      float mean = stat[row * 2], rstd = stat[row * 2 + 1];
#pragma unroll
      for (int j = 0; j < 4; ++j) {
        int n = (4 * wv + j) * 16 + ml;
        float x = (acc[mi][j][r] - mean) * rstd * bf2f(Ps[pg * 512 + n]) + bf2f(Ps[pbe * 512 + n]);
        x = x > 0.f ? x : 0.01f * x;
        As[a_addr(row, n)] = f2bf(x);
      }
    }
  barrier_lds();  // As writes visible
}

// RK4 stage: k = acc + bout; h fp32 regs, ksum packed bf16 pairs; writes y
// into As; on the final stage also writes h_ode to Yb.
static __device__ __forceinline__ void stage_epi(floatx4 (&acc)[2][4], float (&h)[2][4][4],
                                                 unsigned int (&ks)[2][4][2], unsigned short* As,
                                                 unsigned short* Yb, size_t m0,
                                                 const unsigned short* Ps, int stg, bool last,
                                                 int wv, int lane) {
  const int ml = lane & 15, qd = lane >> 4;
  barrier_lds();  // K-loop has no barriers: ensure all waves done reading As
#pragma unroll
  for (int mi = 0; mi < 2; ++mi)
#pragma unroll
    for (int j = 0; j < 4; ++j) {
      int n = (4 * wv + j) * 16 + ml;
      float bias = bf2f(Ps[7 * 512 + n]);
#pragma unroll
      for (int rp = 0; rp < 2; ++rp) {
        float kv0 = acc[mi][j][2 * rp] + bias;
        float kv1 = acc[mi][j][2 * rp + 1] + bias;
        unsigned int pk = ks[mi][j][rp];
        float s0 = bf2f((unsigned short)(pk & 0xffffu));
        float s1 = bf2f((unsigned short)(pk >> 16));
        float h0 = h[mi][j][2 * rp], h1 = h[mi][j][2 * rp + 1];
        float y0, y1;
        if (stg == 0)      { s0 = kv0;        s1 = kv1;        y0 = h0 + 0.125f * kv0; y1 = h1 + 0.125f * kv1; }
        else if (stg == 1) { s0 += 2.f * kv0; s1 += 2.f * kv1; y0 = h0 + 0.125f * kv0; y1 = h1 + 0.125f * kv1; }
        else if (stg == 2) { s0 += 2.f * kv0; s1 += 2.f * kv1; y0 = h0 + 0.25f * kv0;  y1 = h1 + 0.25f * kv1; }
        else {
          h0 += (1.f / 24.f) * (s0 + kv0);  // dt/6, dt=0.25
          h1 += (1.f / 24.f) * (s1 + kv1);
          h[mi][j][2 * rp] = h0; h[mi][j][2 * rp + 1] = h1;
          y0 = h0; y1 = h1;
        }
        ks[mi][j][rp] = (unsigned int)f2bf(s0) | ((unsigned int)f2bf(s1) << 16);
        int row = mi * 16 + 4 * qd + 2 * rp;
        As[a_addr(row, n)] = f2bf(y0);
        As[a_addr(row + 1, n)] = f2bf(y1);
        if (last && stg == 3) {
          Yb[(m0 + row) * 512 + n] = f2bf(y0);
          Yb[(m0 + row + 1) * 512 + n] = f2bf(y1);
        }
      }
    }
  barrier_lds();  // As writes visible
}

__global__ __launch_bounds__(512) void ode_mega(
    unsigned short* Yb, const unsigned short* __restrict__ W1t,
    const unsigned short* __restrict__ W2t, const unsigned short* __restrict__ Wot,
    const float* __restrict__ b1, const float* __restrict__ tr, const float* __restrict__ g1,
    const float* __restrict__ be1, const float* __restrict__ b2, const float* __restrict__ g2,
    const float* __restrict__ be2, const float* __restrict__ bo) {
  __shared__ __align__(16) unsigned short As[16384];  // 32KB tiled A (32 rows)
  __shared__ __align__(16) unsigned short Ps[4096];   // 8KB params
  __shared__ float2 red[256];                         // 2KB: 32 rows x 8 waves
  __shared__ float stat[64];                          // 256B -> ~42.3KB, 2 blocks/CU

  const int tid = threadIdx.x;
  const int lane = tid & 63;
  const int wv = tid >> 6;  // 0..7
  const int ml = lane & 15;
  const int qd = lane >> 4;
  const size_t m0 = (size_t)blockIdx.x * 32;

  // start weight prefetch immediately
  bf16x8 bb[2][4];
  bload(W1t, 0, wv, lane, bb[0]);
  bload(W1t, 1, wv, lane, bb[1]);

  {
    const float* srcs[8] = {b1, tr, g1, be1, b2, g2, be2, bo};
#pragma unroll
    for (int v = 0; v < 8; ++v) Ps[v * 512 + tid] = f2bf(srcs[v][tid]);
  }
  // stage As: thread owns row r = tid>>4, chunks c = i*16 + (tid&15)
  {
    int r = tid >> 4;  // 0..31
#pragma unroll
    for (int i = 0; i < 4; ++i) {
      int c = i * 16 + (tid & 15);
      uint4 v = *(const uint4*)(Yb + (m0 + r) * 512 + c * 8);
      int dst = (((r >> 4) * 16 + (c >> 2)) * 4 + (c & 3)) * 128 + (r & 15) * 8;
      *(uint4*)(As + dst) = v;
    }
  }
  barrier_lds();

  float h[2][4][4];          // fp32 ODE state, MFMA C-layout
  unsigned int ks[2][4][2];  // RK4 ksum, packed bf16 pairs
#pragma unroll
  for (int mi = 0; mi < 2; ++mi)
#pragma unroll
    for (int j = 0; j < 4; ++j) {
      ks[mi][j][0] = 0u; ks[mi][j][1] = 0u;
      int n = (4 * wv + j) * 16 + ml;
#pragma unroll
      for (int r = 0; r < 4; ++r) h[mi][j][r] = bf2f(As[a_addr(mi * 16 + 4 * qd + r, n)]);
    }

  for (int e = 0; e < 16; ++e) {  // 4 RK4 steps x 4 stages
    int stg = e & 3;
    float tval = 0.25f * (float)(e >> 2) + ((stg == 3) ? 0.25f : (stg ? 0.125f : 0.f));
    floatx4 acc[2][4];
    gemmS(W1t, W2t, As, wv, lane, bb, acc);
    ln_epi(acc, As, Ps, 0, 2, 3, true, tval, wv, lane, tid, red, stat);
    gemmS(W2t, Wot, As, wv, lane, bb, acc);
    ln_epi(acc, As, Ps, 4, 5, 6, false, 0.f, wv, lane, tid, red, stat);
    gemmS(Wot, W1t, As, wv, lane, bb, acc);  // preloads next eval's W1
    stage_epi(acc, h, ks, As, Yb, m0, Ps, stg, e == 15, wv, lane);
  }
}

// ---------------------------------------------------------------------------
// GRU step (unchanged): gi = y_t @ W_ih, gh = h_prev @ W_hh, gates.
// grid (32, 8): 32 rows x 64 gate-cols per block, 4 waves.
// ---------------------------------------------------------------------------
__global__ __launch_bounds__(256) void gru_step(
    const unsigned short* __restrict__ Yt, const float* __restrict__ hprev,
    float* __restrict__ hnew, const unsigned short* __restrict__ Wiht,
    const unsigned short* __restrict__ Whht, const float* __restrict__ bih,
    const float* __restrict__ bhh) {
  __shared__ __align__(16) unsigned short Ay[32 * BP];
  __shared__ __align__(16) unsigned short Ah[32 * BP];
  __shared__ __align__(16) unsigned short Bg[6 * 64 * BP];
  const int tid = threadIdx.x, lane = tid & 63, wv = tid >> 6;
  const int ml = lane & 15, qd = lane >> 4;
  const int m0 = blockIdx.x * 32;
  const int j0 = blockIdx.y * 64;

  floatx4 acc[2][6];
#pragma unroll
  for (int mi = 0; mi < 2; ++mi)
#pragma unroll
    for (int g = 0; g < 6; ++g) acc[mi][g] = 0.f;

  for (int kk = 0; kk < 16; ++kk) {
    __syncthreads();
#pragma unroll
    for (int c = 0; c < 7; ++c) {
      int id = c * 256 + tid;
      if (id < 128) {
        int r = id >> 2, kc = id & 3;
        *(uint4*)(Ay + r * BP + kc * 8) =
            *(const uint4*)(Yt + (size_t)(m0 + r) * 512 + kk * 32 + kc * 8);
      } else if (id < 256) {
        int id2 = id - 128;
        int r = id2 >> 2, kc = id2 & 3;
        const float* s = hprev + (size_t)(m0 + r) * 512 + kk * 32 + kc * 8;
        unsigned short o[8] __attribute__((aligned(16)));
#pragma unroll
        for (int j = 0; j < 8; ++j) o[j] = f2bf(s[j]);
        *(uint4*)(Ah + r * BP + kc * 8) = *(const uint4*)o;
      } else {
        int id2 = id - 256;
        int g = id2 >> 8;
        int rem = id2 & 255;
        int r = rem >> 2, kc = rem & 3;
        const unsigned short* mat = (g < 3) ? Wiht : Whht;
        int gate = (g < 3) ? g : (g - 3);
        *(uint4*)(Bg + g * (64 * BP) + r * BP + kc * 8) =
            *(const uint4*)(mat + (size_t)(gate * 512 + j0 + r) * 512 + kk * 32 + kc * 8);
      }
    }
    __syncthreads();
    bf16x8 ay[2], ah[2];
#pragma unroll
    for (int mi = 0; mi < 2; ++mi) {
      ay[mi] = *(const bf16x8*)&Ay[(16 * mi + ml) * BP + qd * 8];
      ah[mi] = *(const bf16x8*)&Ah[(16 * mi + ml) * BP + qd * 8];
    }
#pragma unroll
    for (int g = 0; g < 6; ++g) {
      bf16x8 b = *(const bf16x8*)&Bg[g * (64 * BP) + (16 * wv + ml) * BP + qd * 8];
#pragma unroll
      for (int mi = 0; mi < 2; ++mi)
        acc[mi][g] = __builtin_amdgcn_mfma_f32_16x16x32_bf16((g < 3) ? ay[mi] : ah[mi], b,
                                                             acc[mi][g], 0, 0, 0);
    }
  }
  int j = j0 + 16 * wv + ml;
  float bi_r = bih[j], bi_z = bih[512 + j], bi_n = bih[1024 + j];
  float bh_r = bhh[j], bh_z = bhh[512 + j], bh_n = bhh[1024 + j];
#pragma unroll
  for (int mi = 0; mi < 2; ++mi)
#pragma unroll
    for (int r = 0; r < 4; ++r) {
      size_t row = (size_t)(m0 + 16 * mi + 4 * qd + r);
      float rg = acc[mi][0][r] + bi_r + acc[mi][3][r] + bh_r;
      rg = 1.f / (1.f + __expf(-rg));
      float zg = acc[mi][1][r] + bi_z + acc[mi][4][r] + bh_z;
      zg = 1.f / (1.f + __expf(-zg));
      float ng = tanhf(acc[mi][2][r] + bi_n + rg * (acc[mi][5][r] + bh_n));
      float hp = hprev[row * 512 + j];
      hnew[row * 512 + j] = (1.f - zg) * ng + zg * hp;
    }
}

__global__ void zero_h(float* hf) {
  int i = blockIdx.x * 256 + threadIdx.x;
  hf[i] = 0.f;
}

// ---------------------------------------------------------------------------
extern "C" void kernel_launch(void* const* d_in, const int* in_sizes, int n_in,
                              void* d_out, int out_size, void* d_ws, size_t ws_size,
                              hipStream_t stream) {
  (void)in_sizes; (void)n_in; (void)out_size; (void)ws_size;
  const float* xs    = (const float*)d_in[0];
  const float* obsW  = (const float*)d_in[1];
  const float* obsb  = (const float*)d_in[2];
  const float* obsg  = (const float*)d_in[3];
  const float* obsbe = (const float*)d_in[4];
  const float* W1    = (const float*)d_in[5];
  const float* b1    = (const float*)d_in[6];
  const float* g1    = (const float*)d_in[7];
  const float* be1   = (const float*)d_in[8];
  const float* W2    = (const float*)d_in[9];
  const float* b2    = (const float*)d_in[10];
  const float* g2    = (const float*)d_in[11];
  const float* be2   = (const float*)d_in[12];
  const float* Wo    = (const float*)d_in[13];
  const float* bo    = (const float*)d_in[14];
  const float* Wih   = (const float*)d_in[15];
  const float* bih   = (const float*)d_in[16];
  const float* Whh   = (const float*)d_in[17];
  const float* bhh   = (const float*)d_in[18];

  char* p = (char*)d_ws;
  auto take = [&](size_t bytes) { char* q = p; p += (bytes + 255) & ~(size_t)255; return q; };
  unsigned short* W1t  = (unsigned short*)take((size_t)512 * 512 * 2);
  unsigned short* W2t  = (unsigned short*)take((size_t)512 * 512 * 2);
  unsigned short* Wot  = (unsigned short*)take((size_t)512 * 512 * 2);
  unsigned short* Wiht = (unsigned short*)take((size_t)1536 * 512 * 2);
  unsigned short* Whht = (unsigned short*)take((size_t)1536 * 512 * 2);
  float* hf0 = (float*)take((size_t)1024 * 512 * 4);
  float* hf1 = (float*)take((size_t)1024 * 512 * 4);
  unsigned short* Yb = (unsigned short*)take((size_t)65536 * 512 * 2);

  dim3 tb(32, 8);
  tile_weight<<<128, 256, 0, stream>>>(W1, W1t);  // first 512 of 513 rows
  tile_weight<<<128, 256, 0, stream>>>(W2, W2t);
  tile_weight<<<128, 256, 0, stream>>>(Wo, Wot);
  transpose_f2b<<<dim3(48, 16), tb, 0, stream>>>(Wih, Wiht, 512, 1536);
  transpose_f2b<<<dim3(48, 16), tb, 0, stream>>>(Whh, Whht, 512, 1536);

  obs_embed<<<16384, 256, 0, stream>>>(xs, obsW, obsb, obsg, obsbe, Yb);

  // tr = W1 row 512 (time row), folded into layer-1 bias per eval.
  ode_mega<<<2048, 512, 0, stream>>>(Yb, W1t, W2t, Wot, b1, W1 + 512 * 512, g1, be1, b2, g2,
                                     be2, bo);

  zero_h<<<2048, 256, 0, stream>>>(hf0);
  float* hf[2] = {hf0, hf1};
  for (int t = 0; t < 64; ++t) {
    int s = t & 1, d = s ^ 1;
    float* hn = (t == 63) ? (float*)d_out : hf[d];
    gru_step<<<dim3(32, 8), 256, 0, stream>>>(Yb + (size_t)t * 1024 * 512, hf[s], hn, Wiht, Whht,
                                              bih, bhh);
  }
}